// Round 1
// baseline (268.999 us; speedup 1.0000x reference)
//
#include <hip/hip_runtime.h>

typedef __bf16 bf16x8 __attribute__((ext_vector_type(8)));
typedef float f32x4 __attribute__((ext_vector_type(4)));
typedef unsigned short u16x4 __attribute__((ext_vector_type(4)));

#define NBATCH 8
#define LPTS   16384
#define CDIM   256
#define KANC   64
#define DIN    512
#define H1DIM  128
#define H2DIM  256
#define TM     64

__device__ __forceinline__ unsigned short f2bf(float f){
  unsigned int u = __builtin_bit_cast(unsigned int, f);
  u += 0x7fffu + ((u >> 16) & 1u);
  return (unsigned short)(u >> 16);
}

// Convert + transpose weights into ws as bf16:
//  wt[0      .. 65536)  = W1T [128][512]
//  wt[65536  .. 98304)  = W2T [256][128]
//  wt[98304  .. 163840) = W3T [256][256]
__global__ __launch_bounds__(256) void prep_weights(
    const float* __restrict__ W1, const float* __restrict__ W2,
    const float* __restrict__ W3, unsigned short* __restrict__ wt){
  int id = blockIdx.x * 256 + threadIdx.x;
  if (id < 65536){
    int r = id >> 9, c = id & 511;
    wt[id] = f2bf(W1[c * 128 + r]);
  } else if (id < 98304){
    int t = id - 65536; int r = t >> 7, c = t & 127;
    wt[id] = f2bf(W2[c * 256 + r]);
  } else if (id < 163840){
    int t = id - 98304; int r = t >> 8, c = t & 255;
    wt[id] = f2bf(W3[c * 256 + r]);
  }
}

__global__ __launch_bounds__(512, 4) void fused(
    const float* __restrict__ feat0, const float* __restrict__ feat1,
    const float* __restrict__ pts0, const float* __restrict__ pts1,
    const int* __restrict__ anc_i, const int* __restrict__ anc_j,
    const float* __restrict__ b1, const float* __restrict__ b2,
    const float* __restrict__ b3, const unsigned short* __restrict__ wt,
    float* __restrict__ out)
{
  // 80 KiB total -> 2 blocks/CU. h2 aliases xs (xs dead after GEMM1);
  // anchors alias h1s (anchors dead before h1s first written).
  __shared__ unsigned short xs[TM * DIN];     // 64 KiB
  __shared__ unsigned short h1s[TM * H1DIM];  // 16 KiB
  unsigned short* h2s = xs;
  float* anc = (float*)h1s;

  const int tid  = threadIdx.x;
  const int wg   = blockIdx.x;
  const int strm = wg >> 11;
  const int n    = (wg >> 8) & 7;
  const int l0   = (wg & 255) * TM;

  const float* feat = strm ? feat1 : feat0;
  const float* pts  = strm ? pts1 : pts0;
  const int*   anci = strm ? anc_j : anc_i;

  // anchors -> LDS (f32)
  if (tid < KANC){
    int ai = anci[n * KANC + tid];
    const float* pp = pts + ((size_t)n * LPTS + ai) * 3;
    anc[tid*3+0] = pp[0]; anc[tid*3+1] = pp[1]; anc[tid*3+2] = pp[2];
  }

  // ---- Phase A: feat tile -> xs[:, 0:256) (bf16, swizzled)
  {
    const float4* fb = (const float4*)(feat + ((size_t)n * LPTS + l0) * CDIM);
    #pragma unroll
    for (int it = 0; it < 8; ++it){
      int flat = it * 512 + tid;          // 4096 float4 in tile
      int r = flat >> 6, c4 = flat & 63;
      float4 v = fb[flat];
      int e = (r * DIN + c4 * 4) ^ ((r & 7) << 3);
      u16x4 pk = { f2bf(v.x), f2bf(v.y), f2bf(v.z), f2bf(v.w) };
      *(u16x4*)&xs[e] = pk;
    }
  }
  __syncthreads();

  // ---- Phase B: structured features -> xs[:, 256:512)
  // thread (l,c): owns point l, component c; denom = sum_k |f| is thread-local.
  if (tid < 256){
    int l = tid >> 2, c = tid & 3;
    const float* pp = pts + ((size_t)n * LPTS + l0 + l) * 3;
    float px = pp[0], py = pp[1], pz = pp[2];
    float s = 0.f;
    for (int k = 0; k < KANC; ++k){
      float dx = px - anc[k*3], dy = py - anc[k*3+1], dz = pz - anc[k*3+2];
      float d2 = dx*dx + dy*dy + dz*dz;
      float v = (c==0) ? dx : (c==1) ? dy : (c==2) ? dz : d2;
      s += fabsf(v);
    }
    float inv = 1.f / s;
    for (int k = 0; k < KANC; ++k){
      float dx = px - anc[k*3], dy = py - anc[k*3+1], dz = pz - anc[k*3+2];
      float d2 = dx*dx + dy*dy + dz*dz;
      float v = (c==0) ? dx : (c==1) ? dy : (c==2) ? dz : d2;
      int e = (l * DIN + 256 + c * 64 + k) ^ ((l & 7) << 3);
      xs[e] = f2bf(v * inv);
    }
  }
  __syncthreads();

  const int lane = tid & 63;
  const int w    = tid >> 6;     // 8 waves
  const int lr   = lane & 15;
  const int lg   = lane >> 4;

  // ---- GEMM1: xs[64,512] @ W1 -> relu -> h1s[64,128]
  {
    f32x4 acc[4] = {};
    const int col = w * 16 + lr;                  // wave owns 16 cols
    const unsigned short* wrow = wt + col * DIN;
    #pragma unroll 4
    for (int kk = 0; kk < 16; ++kk){
      int kb = kk * 32 + lg * 8;
      bf16x8 b = *(const bf16x8*)&wrow[kb];
      #pragma unroll
      for (int m = 0; m < 4; ++m){
        int row = m * 16 + lr;
        int e = (row * DIN + kb) ^ ((row & 7) << 3);
        bf16x8 a = *(const bf16x8*)&xs[e];
        acc[m] = __builtin_amdgcn_mfma_f32_16x16x32_bf16(a, b, acc[m], 0, 0, 0);
      }
    }
    float bias = b1[col];
    #pragma unroll
    for (int m = 0; m < 4; ++m){
      #pragma unroll
      for (int r = 0; r < 4; ++r){
        int row = m * 16 + lg * 4 + r;
        float v = fmaxf(acc[m][r] + bias, 0.f);
        int e = (row * H1DIM + col) ^ ((row & 7) << 3);
        h1s[e] = f2bf(v);
      }
    }
  }
  __syncthreads();

  // ---- GEMM2: h1s[64,128] @ W2 -> relu -> h2s[64,256]  (h2s aliases xs)
  {
    const unsigned short* w2t = wt + 65536;
    f32x4 acc[4][2] = {};
    const int col0 = w * 32;
    #pragma unroll
    for (int kk = 0; kk < 4; ++kk){
      int kb = kk * 32 + lg * 8;
      bf16x8 bf0 = *(const bf16x8*)&w2t[(col0 + lr) * H1DIM + kb];
      bf16x8 bf1 = *(const bf16x8*)&w2t[(col0 + 16 + lr) * H1DIM + kb];
      #pragma unroll
      for (int m = 0; m < 4; ++m){
        int row = m * 16 + lr;
        int e = (row * H1DIM + kb) ^ ((row & 7) << 3);
        bf16x8 a = *(const bf16x8*)&h1s[e];
        acc[m][0] = __builtin_amdgcn_mfma_f32_16x16x32_bf16(a, bf0, acc[m][0], 0, 0, 0);
        acc[m][1] = __builtin_amdgcn_mfma_f32_16x16x32_bf16(a, bf1, acc[m][1], 0, 0, 0);
      }
    }
    __syncthreads();   // all h1s reads done AND xs (GEMM1 A-reads) fully retired
    #pragma unroll
    for (int nt = 0; nt < 2; ++nt){
      int col = col0 + nt * 16 + lr;
      float bias = b2[col];
      #pragma unroll
      for (int m = 0; m < 4; ++m){
        #pragma unroll
        for (int r = 0; r < 4; ++r){
          int row = m * 16 + lg * 4 + r;
          float v = fmaxf(acc[m][nt][r] + bias, 0.f);
          int e = (row * H2DIM + col) ^ ((row & 7) << 3);
          h2s[e] = f2bf(v);
        }
      }
    }
  }
  __syncthreads();

  // ---- GEMM3: h2s[64,256] @ W3 -> + b3 -> out (f32)
  {
    const unsigned short* w3t = wt + 98304;
    f32x4 acc[4][2] = {};
    const int col0 = w * 32;
    #pragma unroll
    for (int kk = 0; kk < 8; ++kk){
      int kb = kk * 32 + lg * 8;
      bf16x8 bf0 = *(const bf16x8*)&w3t[(col0 + lr) * H2DIM + kb];
      bf16x8 bf1 = *(const bf16x8*)&w3t[(col0 + 16 + lr) * H2DIM + kb];
      #pragma unroll
      for (int m = 0; m < 4; ++m){
        int row = m * 16 + lr;
        int e = (row * H2DIM + kb) ^ ((row & 7) << 3);
        bf16x8 a = *(const bf16x8*)&h2s[e];
        acc[m][0] = __builtin_amdgcn_mfma_f32_16x16x32_bf16(a, bf0, acc[m][0], 0, 0, 0);
        acc[m][1] = __builtin_amdgcn_mfma_f32_16x16x32_bf16(a, bf1, acc[m][1], 0, 0, 0);
      }
    }
    float* ob = out + (((size_t)strm * NBATCH + n) * LPTS + l0) * CDIM;
    #pragma unroll
    for (int nt = 0; nt < 2; ++nt){
      int col = col0 + nt * 16 + lr;
      float bias = b3[col];
      #pragma unroll
      for (int m = 0; m < 4; ++m){
        #pragma unroll
        for (int r = 0; r < 4; ++r){
          int row = m * 16 + lg * 4 + r;
          ob[(size_t)row * CDIM + col] = acc[m][nt][r] + bias;
        }
      }
    }
  }
}

extern "C" void kernel_launch(void* const* d_in, const int* in_sizes, int n_in,
                              void* d_out, int out_size, void* d_ws, size_t ws_size,
                              hipStream_t stream){
  const float* feat0 = (const float*)d_in[0];
  const float* feat1 = (const float*)d_in[1];
  const float* pts0  = (const float*)d_in[2];
  const float* pts1  = (const float*)d_in[3];
  const int*   anci  = (const int*)d_in[4];
  const int*   ancj  = (const int*)d_in[5];
  const float* W1    = (const float*)d_in[6];
  const float* b1    = (const float*)d_in[7];
  const float* W2    = (const float*)d_in[8];
  const float* b2    = (const float*)d_in[9];
  const float* W3    = (const float*)d_in[10];
  const float* b3    = (const float*)d_in[11];
  unsigned short* wt = (unsigned short*)d_ws;
  float* out = (float*)d_out;

  prep_weights<<<640, 256, 0, stream>>>(W1, W2, W3, wt);
  fused<<<4096, 512, 0, stream>>>(feat0, feat1, pts0, pts1, anci, ancj,
                                  b1, b2, b3, wt, out);
}